// Round 13
// baseline (136.505 us; speedup 1.0000x reference)
//
#include <hip/hip_runtime.h>
#include <hip/hip_bf16.h>

#define J_DIM 25
#define T_DIM 120
#define O_DIM 64
#define KPAD  328        // bf16 per ys/Wf row; 656 B = 164 dwords == 4 mod 32 -> 2-way banks
#define TB    16         // t-rows per tile
#define WROWS 20         // staged window rows (tloc + w <= 19)
#define XPAD  20         // xs row pad (floats)
#define NTILE 12800      // 64 * 25 * 8
#define GRID  2048       // persistent blocks (8/CU)

typedef __attribute__((ext_vector_type(8))) short bf16x8;
typedef __attribute__((ext_vector_type(4))) float f32x4;

__device__ __forceinline__ unsigned f2bf(float f) {
    union { float f; unsigned u; } v; v.f = f;
    return (v.u + 0x7FFFu + ((v.u >> 16) & 1u)) >> 16;
}
__device__ __forceinline__ unsigned pk2(float lo, float hi) {
    __hip_bfloat162 h = __float22bfloat162_rn(float2{lo, hi});
    unsigned u;
    __builtin_memcpy(&u, &h, 4);
    return u;
}

// ---- W (306x64 f32) -> Wf[o][k], k = 18a + b; b<17: 0.5*W2[a,b]; b==17: W1[a] ----
__global__ void wprep(const float* __restrict__ W, unsigned short* __restrict__ Wf) {
    int i = blockIdx.x * 256 + threadIdx.x;
    if (i >= O_DIM * KPAD) return;
    int o = i / KPAD, k = i % KPAD;
    int a = k / 18, b = k % 18;
    float v = 0.0f;
    if (k < 306) v = (b == 17) ? W[a * O_DIM + o] : 0.5f * W[(17 + 17 * a + b) * O_DIM + o];
    Wf[o * KPAD + k] = (unsigned short)f2bf(v);
}

// ---- main: 2048 persistent 128-thread blocks, grid-stride over 12800 tiles ----
// launch_bounds 2nd arg must stay <= 4: higher clamps VGPR below need -> scratch
// spill catastrophe (measured R6: 40 VGPR / 200+ MB; R10 same).
__global__ __launch_bounds__(128, 4) void sig_mfma(
    const float* __restrict__ x, const unsigned short* __restrict__ Wf,
    const float* __restrict__ bias, float* __restrict__ out)
{
    __shared__ float xs[2][WROWS][XPAD];         // 3,200 B (double-buffered)
    __shared__ unsigned short ys[TB * KPAD];     // 10,496 B  (total 13.7 KB -> 8+ blk/CU)

    const int tid = threadIdx.x;
    const int wave = tid >> 6, lane = tid & 63;
    const int l15 = lane & 15, l4 = lane >> 4;
    const int tl8 = lane & 7, q = lane >> 3;
    const int tloc = wave * 8 + tl8;             // 0..15

    // ---- prologue: stage first tile's xs into buf 0; zero ys pad ----
    {
        int tile = blockIdx.x;
        int chunk = tile & 7, j = (tile >> 3) % J_DIM, n = tile / (8 * J_DIM);
        int t0 = (chunk < 7) ? chunk * 16 : 104;
        const float* xb = x + ((size_t)(n * 16) * J_DIM + j) * T_DIM;
        for (int idx = tid; idx < 16 * WROWS; idx += 128) {
            int c = idx / WROWS, i = idx % WROWS;
            int st = min(max(t0 - 2 + i, 0), T_DIM - 1);
            xs[0][i][c] = xb[(size_t)c * J_DIM * T_DIM + st];
        }
    }
    if (tid < TB * 3) {
        int r = tid / 3, p = tid % 3;
        *(uint4*)((char*)ys + r * 656 + 608 + p * 16) = uint4{0, 0, 0, 0};
    }
    __syncthreads();

    int cur = 0;
    #pragma unroll 1
    for (int tile = blockIdx.x; tile < NTILE; tile += GRID) {
        const int chunk = tile & 7;
        const int j = (tile >> 3) % J_DIM;
        const int n = tile / (8 * J_DIM);
        const int t0 = (chunk < 7) ? chunk * 16 : 104;

        // ---- A: issue next tile's x loads into registers (consumed after phase 2) ----
        const int ntile = tile + GRID;
        const bool haveNext = (ntile < NTILE);
        float rr0 = 0.f, rr1 = 0.f, rr2 = 0.f;
        if (haveNext) {
            int nchunk = ntile & 7, nj = (ntile >> 3) % J_DIM, nn = ntile / (8 * J_DIM);
            int nt0 = (nchunk < 7) ? nchunk * 16 : 104;
            const float* xb = x + ((size_t)(nn * 16) * J_DIM + nj) * T_DIM;
            {
                int idx = tid;                       // < 320 always
                int c = idx / WROWS, i = idx % WROWS;
                int st = min(max(nt0 - 2 + i, 0), T_DIM - 1);
                rr0 = xb[(size_t)c * J_DIM * T_DIM + st];
            }
            {
                int idx = tid + 128;                 // < 320 always
                int c = idx / WROWS, i = idx % WROWS;
                int st = min(max(nt0 - 2 + i, 0), T_DIM - 1);
                rr1 = xb[(size_t)c * J_DIM * T_DIM + st];
            }
            if (tid + 256 < 16 * WROWS) {
                int idx = tid + 256;
                int c = idx / WROWS, i = idx % WROWS;
                int st = min(max(nt0 - 2 + i, 0), T_DIM - 1);
                rr2 = xb[(size_t)c * J_DIM * T_DIM + st];
            }
        }

        // ---- B: phase 1 — thread (tloc, q) -> S2 rows a = 2q,2q+1 (+ row 16 by q==0) ----
        // S2[a,b] = sum_w h_w[a] * p_w[b],  h = (-p1, p0-p2, p1-p3, p2-p4, p3+p4)
        {
            const int t = t0 + tloc;
            const int start = max(t - 2, 0), end = min(t + 3, T_DIM);
            const float inv = 1.0f / (float)(end - start - 1);
            float ptv[5];
            #pragma unroll
            for (int w = 0; w < 5; ++w) {
                int pcw = min(max(t - 2 + w, 0), T_DIM - 1);
                ptv[w] = (float)(pcw - start) * inv;
            }
            float pa0[5], pa1[5];
            #pragma unroll
            for (int w = 0; w < 5; ++w) {
                float2 pr = *(const float2*)&xs[cur][tloc + w][2 * q];
                pa0[w] = pr.x; pa1[w] = pr.y;
            }
            float h0[5], h1[5], ht[5];
            h0[0] = -pa0[1];          h1[0] = -pa1[1];          ht[0] = -ptv[1];
            h0[1] = pa0[0] - pa0[2];  h1[1] = pa1[0] - pa1[2];  ht[1] = ptv[0] - ptv[2];
            h0[2] = pa0[1] - pa0[3];  h1[2] = pa1[1] - pa1[3];  ht[2] = ptv[1] - ptv[3];
            h0[3] = pa0[2] - pa0[4];  h1[3] = pa1[2] - pa1[4];  ht[3] = ptv[2] - ptv[4];
            h0[4] = pa0[3] + pa0[4];  h1[4] = pa1[3] + pa1[4];  ht[4] = ptv[3] + ptv[4];

            unsigned u0[9], u1[9], ut[9];
            float accp0 = 0, accp1 = 0, accpt = 0;
            #pragma unroll
            for (int hb = 0; hb < 2; ++hb) {
                float4 xw[5][2];
                #pragma unroll
                for (int w = 0; w < 5; ++w) {
                    const float* rw = &xs[cur][tloc + w][0];
                    xw[w][0] = *(const float4*)(rw + 8 * hb);
                    xw[w][1] = *(const float4*)(rw + 8 * hb + 4);
                }
                #pragma unroll
                for (int b8 = 0; b8 < 8; ++b8) {
                    float pb[5];
                    #pragma unroll
                    for (int w = 0; w < 5; ++w) {
                        float4 v = xw[w][b8 >> 2];
                        pb[w] = ((b8 & 3) == 0) ? v.x : ((b8 & 3) == 1) ? v.y
                              : ((b8 & 3) == 2) ? v.z : v.w;
                    }
                    float a0 = h0[0] * pb[0], a1 = h1[0] * pb[0], at = ht[0] * pb[0];
                    #pragma unroll
                    for (int w = 1; w < 5; ++w) {
                        a0 = fmaf(h0[w], pb[w], a0);
                        a1 = fmaf(h1[w], pb[w], a1);
                        at = fmaf(ht[w], pb[w], at);
                    }
                    const int b = hb * 8 + b8;
                    if (b & 1) {
                        const int m = b >> 1;
                        u0[m] = pk2(accp0, a0);
                        u1[m] = pk2(accp1, a1);
                        ut[m] = pk2(accpt, at);
                    } else { accp0 = a0; accp1 = a1; accpt = at; }
                }
            }
            {   // b = 16 (time column) + S1 slot
                float a0 = h0[0] * ptv[0], a1 = h1[0] * ptv[0], at = ht[0] * ptv[0];
                #pragma unroll
                for (int w = 1; w < 5; ++w) {
                    a0 = fmaf(h0[w], ptv[w], a0);
                    a1 = fmaf(h1[w], ptv[w], a1);
                    at = fmaf(ht[w], ptv[w], at);
                }
                u0[8] = pk2(a0, pa0[4]);
                u1[8] = pk2(a1, pa1[4]);
                ut[8] = pk2(at, ptv[4]);
            }
            char* yr = (char*)ys + tloc * 656 + 72 * q;  // rows 2q,2q+1: contiguous 72 B
            *(uint2*)(yr +  0) = uint2{u0[0], u0[1]};
            *(uint2*)(yr +  8) = uint2{u0[2], u0[3]};
            *(uint2*)(yr + 16) = uint2{u0[4], u0[5]};
            *(uint2*)(yr + 24) = uint2{u0[6], u0[7]};
            *(uint2*)(yr + 32) = uint2{u0[8], u1[0]};
            *(uint2*)(yr + 40) = uint2{u1[1], u1[2]};
            *(uint2*)(yr + 48) = uint2{u1[3], u1[4]};
            *(uint2*)(yr + 56) = uint2{u1[5], u1[6]};
            *(uint2*)(yr + 64) = uint2{u1[7], u1[8]};
            if (q == 0) {                                // row a=16 at bytes [576,612)
                char* yr16 = (char*)ys + tloc * 656 + 576;
                *(uint2*)(yr16 +  0) = uint2{ut[0], ut[1]};
                *(uint2*)(yr16 +  8) = uint2{ut[2], ut[3]};
                *(uint2*)(yr16 + 16) = uint2{ut[4], ut[5]};
                *(uint2*)(yr16 + 24) = uint2{ut[6], ut[7]};
                *(unsigned*)(yr16 + 32) = ut[8];
            }
        }
        __syncthreads();

        // ---- D: phase 2 — 2 waves x 2 o-groups; B-frags from global (L2-hot) ----
        {
            f32x4 acc[2];
            #pragma unroll
            for (int cc = 0; cc < 2; ++cc) {
                float bv = bias[(wave * 2 + cc) * 16 + l15];
                acc[cc] = f32x4{bv, bv, bv, bv};
            }
            const char* Ab = (const char*)ys + l15 * 656 + l4 * 16;
            const unsigned short* Bb = Wf + (size_t)l15 * KPAD + l4 * 8;
            #pragma unroll
            for (int kk = 0; kk < 10; ++kk) {
                bf16x8 af = *(const bf16x8*)(Ab + kk * 64);
                #pragma unroll
                for (int cc = 0; cc < 2; ++cc) {
                    bf16x8 bfr = *(const bf16x8*)(Bb + (size_t)((wave * 2 + cc) * 16) * KPAD + kk * 32);
                    acc[cc] = __builtin_amdgcn_mfma_f32_16x16x32_bf16(af, bfr, acc[cc], 0, 0, 0);
                }
            }
            const int tg = t0 + l4 * 4;
            #pragma unroll
            for (int cc = 0; cc < 2; ++cc) {
                int o = (wave * 2 + cc) * 16 + l15;
                *(f32x4*)(out + ((size_t)(n * O_DIM + o) * J_DIM + j) * T_DIM + tg) = acc[cc];
            }
        }

        // ---- E: write prefetched regs into the other xs buffer ----
        if (haveNext) {
            const int nb = cur ^ 1;
            {
                int idx = tid;
                xs[nb][idx % WROWS][idx / WROWS] = rr0;
            }
            {
                int idx = tid + 128;
                xs[nb][idx % WROWS][idx / WROWS] = rr1;
            }
            if (tid + 256 < 16 * WROWS) {
                int idx = tid + 256;
                xs[nb][idx % WROWS][idx / WROWS] = rr2;
            }
        }
        __syncthreads();
        cur ^= 1;
    }
}

extern "C" void kernel_launch(void* const* d_in, const int* in_sizes, int n_in,
                              void* d_out, int out_size, void* d_ws, size_t ws_size,
                              hipStream_t stream) {
    const float* x = (const float*)d_in[0];
    const float* W = (const float*)d_in[1];
    const float* b = (const float*)d_in[2];
    float* out = (float*)d_out;
    unsigned short* Wf = (unsigned short*)d_ws;   // 64*328*2 = 41,984 B

    wprep<<<(O_DIM * KPAD + 255) / 256, 256, 0, stream>>>(W, Wf);
    sig_mfma<<<GRID, 128, 0, stream>>>(x, Wf, b, out);
}

// Round 14
// 44.341 us; speedup vs baseline: 3.0785x; 3.0785x over previous
//
#include <hip/hip_runtime.h>
#include <hip/hip_bf16.h>

#define J_DIM 25
#define T_DIM 120
#define O_DIM 64
#define KPAD  328        // bf16 per ys/Wf row; 656 B = 164 dwords == 4 mod 32 -> 2-way banks
#define TB    64         // t-rows per block
#define WROWS 68         // staged window rows (row + w <= 67)
#define XPAD  20         // xs row pad (floats)

typedef __attribute__((ext_vector_type(8))) short bf16x8;
typedef __attribute__((ext_vector_type(4))) float f32x4;

__device__ __forceinline__ unsigned f2bf(float f) {
    union { float f; unsigned u; } v; v.f = f;
    return (v.u + 0x7FFFu + ((v.u >> 16) & 1u)) >> 16;
}
__device__ __forceinline__ unsigned pk2(float lo, float hi) {
    __hip_bfloat162 h = __float22bfloat162_rn(float2{lo, hi});
    unsigned u;
    __builtin_memcpy(&u, &h, 4);
    return u;
}

// ---- W (306x64 f32) -> Wf[o][k], k = 18a + b; b<17: 0.5*W2[a,b]; b==17: W1[a] ----
__global__ void wprep(const float* __restrict__ W, unsigned short* __restrict__ Wf) {
    int i = blockIdx.x * 256 + threadIdx.x;
    if (i >= O_DIM * KPAD) return;
    int o = i / KPAD, k = i % KPAD;
    int a = k / 18, b = k % 18;
    float v = 0.0f;
    if (k < 306) v = (b == 17) ? W[a * O_DIM + o] : 0.5f * W[(17 + 17 * a + b) * O_DIM + o];
    Wf[o * KPAD + k] = (unsigned short)f2bf(v);
}

// ---- main: block = (n, j, 64-row half); 256 threads; flat 2-barrier structure ----
// Lessons baked in: launch_bounds cap must exceed ~90 VGPR (R6/R10: clamping ->
// scratch catastrophe); phase-1 body must NOT share a loop with cross-phase
// live state (R8/R9/R13 spills); plain slot-loop phase 1 is safe (R12).
__global__ __launch_bounds__(256, 3) void sig_mfma(
    const float* __restrict__ x, const unsigned short* __restrict__ Wf,
    const float* __restrict__ bias, float* __restrict__ out)
{
    __shared__ float xs[WROWS][XPAD];            // 5,440 B
    __shared__ unsigned short ys[TB * KPAD];     // 41,984 B   (total 47.4 KB -> 3 blk/CU)

    const int tid = threadIdx.x;
    const int bid = blockIdx.x;
    const int half = bid & 1;
    const int j = (bid >> 1) % J_DIM;
    const int n = bid / (2 * J_DIM);
    const int t0 = half * 56;                    // halves overlap rows 56..63 (dup stores)
    const int wave = tid >> 6, lane = tid & 63;
    const int l15 = lane & 15, l4 = lane >> 4;

    // ---- stage xs[i][c] = x[n,c,j,clamp(t0-2+i)] ----
    const float* xbase = x + ((size_t)(n * 16) * J_DIM + j) * T_DIM;
    for (int idx = tid; idx < 16 * WROWS; idx += 256) {
        int c = idx / WROWS, i = idx % WROWS;
        int st = min(max(t0 - 2 + i, 0), T_DIM - 1);
        xs[i][c] = xbase[(size_t)c * J_DIM * T_DIM + st];
    }
    // zero pad bytes [608,656) of every row (608-611 re-written by row-16 store)
    if (tid < TB * 3) {
        int r = tid / 3, p = tid % 3;
        *(uint4*)((char*)ys + r * 656 + 608 + p * 16) = uint4{0, 0, 0, 0};
    }
    __syncthreads();

    // ---- phase 1: 512 slots (row 0..63, q 0..7); thread does slots tid, tid+256 ----
    // S2[a,b] = sum_w h_w[a] * p_w[b],  h = (-p1, p0-p2, p1-p3, p2-p4, p3+p4)
    #pragma unroll 1
    for (int s = tid; s < TB * 8; s += 256) {
        const int row = s >> 3, q = s & 7;
        const int t = t0 + row;
        const int start = max(t - 2, 0), end = min(t + 3, T_DIM);
        const float inv = 1.0f / (float)(end - start - 1);
        float ptv[5];
        #pragma unroll
        for (int w = 0; w < 5; ++w) {
            int pcw = min(max(t - 2 + w, 0), T_DIM - 1);
            ptv[w] = (float)(pcw - start) * inv;
        }
        float pa0[5], pa1[5];
        #pragma unroll
        for (int w = 0; w < 5; ++w) {
            float2 pr = *(const float2*)&xs[row + w][2 * q];
            pa0[w] = pr.x; pa1[w] = pr.y;
        }
        float h0[5], h1[5], ht[5];
        h0[0] = -pa0[1];          h1[0] = -pa1[1];          ht[0] = -ptv[1];
        h0[1] = pa0[0] - pa0[2];  h1[1] = pa1[0] - pa1[2];  ht[1] = ptv[0] - ptv[2];
        h0[2] = pa0[1] - pa0[3];  h1[2] = pa1[1] - pa1[3];  ht[2] = ptv[1] - ptv[3];
        h0[3] = pa0[2] - pa0[4];  h1[3] = pa1[2] - pa1[4];  ht[3] = ptv[2] - ptv[4];
        h0[4] = pa0[3] + pa0[4];  h1[4] = pa1[3] + pa1[4];  ht[4] = ptv[3] + ptv[4];

        unsigned u0[9], u1[9], ut[9];
        float accp0 = 0, accp1 = 0, accpt = 0;
        #pragma unroll
        for (int hb = 0; hb < 2; ++hb) {
            float4 xw[5][2];
            #pragma unroll
            for (int w = 0; w < 5; ++w) {
                const float* rw = &xs[row + w][0];
                xw[w][0] = *(const float4*)(rw + 8 * hb);
                xw[w][1] = *(const float4*)(rw + 8 * hb + 4);
            }
            #pragma unroll
            for (int b8 = 0; b8 < 8; ++b8) {
                float pb[5];
                #pragma unroll
                for (int w = 0; w < 5; ++w) {
                    float4 v = xw[w][b8 >> 2];
                    pb[w] = ((b8 & 3) == 0) ? v.x : ((b8 & 3) == 1) ? v.y
                          : ((b8 & 3) == 2) ? v.z : v.w;
                }
                float a0 = h0[0] * pb[0], a1 = h1[0] * pb[0], at = ht[0] * pb[0];
                #pragma unroll
                for (int w = 1; w < 5; ++w) {
                    a0 = fmaf(h0[w], pb[w], a0);
                    a1 = fmaf(h1[w], pb[w], a1);
                    at = fmaf(ht[w], pb[w], at);
                }
                const int b = hb * 8 + b8;
                if (b & 1) {
                    const int m = b >> 1;
                    u0[m] = pk2(accp0, a0);
                    u1[m] = pk2(accp1, a1);
                    ut[m] = pk2(accpt, at);
                } else { accp0 = a0; accp1 = a1; accpt = at; }
            }
        }
        {   // b = 16 (time column) + S1 slot
            float a0 = h0[0] * ptv[0], a1 = h1[0] * ptv[0], at = ht[0] * ptv[0];
            #pragma unroll
            for (int w = 1; w < 5; ++w) {
                a0 = fmaf(h0[w], ptv[w], a0);
                a1 = fmaf(h1[w], ptv[w], a1);
                at = fmaf(ht[w], ptv[w], at);
            }
            u0[8] = pk2(a0, pa0[4]);
            u1[8] = pk2(a1, pa1[4]);
            ut[8] = pk2(at, ptv[4]);
        }
        char* yr = (char*)ys + row * 656 + 72 * q;   // rows 2q,2q+1: contiguous 72 B
        *(uint2*)(yr +  0) = uint2{u0[0], u0[1]};
        *(uint2*)(yr +  8) = uint2{u0[2], u0[3]};
        *(uint2*)(yr + 16) = uint2{u0[4], u0[5]};
        *(uint2*)(yr + 24) = uint2{u0[6], u0[7]};
        *(uint2*)(yr + 32) = uint2{u0[8], u1[0]};
        *(uint2*)(yr + 40) = uint2{u1[1], u1[2]};
        *(uint2*)(yr + 48) = uint2{u1[3], u1[4]};
        *(uint2*)(yr + 56) = uint2{u1[5], u1[6]};
        *(uint2*)(yr + 64) = uint2{u1[7], u1[8]};
        if (q == 0) {                                // row a=16 at bytes [576,612)
            char* yr16 = (char*)ys + row * 656 + 576;
            *(uint2*)(yr16 +  0) = uint2{ut[0], ut[1]};
            *(uint2*)(yr16 +  8) = uint2{ut[2], ut[3]};
            *(uint2*)(yr16 + 16) = uint2{ut[4], ut[5]};
            *(uint2*)(yr16 + 24) = uint2{ut[6], ut[7]};
            *(unsigned*)(yr16 + 32) = ut[8];
        }
    }
    __syncthreads();

    // ---- phase 2: wave = o-quarter; B-frags loaded once, reused over 4 M-tiles ----
    {
        const float bv = bias[wave * 16 + l15];
        const unsigned short* Bb = Wf + (size_t)(wave * 16 + l15) * KPAD + l4 * 8;
        bf16x8 bfrag[10];
        #pragma unroll
        for (int kk = 0; kk < 10; ++kk)
            bfrag[kk] = *(const bf16x8*)(Bb + kk * 32);
        #pragma unroll
        for (int mi = 0; mi < 4; ++mi) {
            const char* Ab = (const char*)ys + (mi * 16 + l15) * 656 + l4 * 16;
            f32x4 acc = f32x4{bv, bv, bv, bv};
            #pragma unroll
            for (int kk = 0; kk < 10; ++kk) {
                bf16x8 af = *(const bf16x8*)(Ab + kk * 64);
                acc = __builtin_amdgcn_mfma_f32_16x16x32_bf16(af, bfrag[kk], acc, 0, 0, 0);
            }
            const int tg = t0 + mi * 16 + l4 * 4;    // row = l4*4 + reg -> t
            float* op = out + ((size_t)(n * O_DIM + wave * 16 + l15) * J_DIM + j) * T_DIM + tg;
            *(f32x4*)op = acc;
        }
    }
}

extern "C" void kernel_launch(void* const* d_in, const int* in_sizes, int n_in,
                              void* d_out, int out_size, void* d_ws, size_t ws_size,
                              hipStream_t stream) {
    const float* x = (const float*)d_in[0];
    const float* W = (const float*)d_in[1];
    const float* b = (const float*)d_in[2];
    float* out = (float*)d_out;
    unsigned short* Wf = (unsigned short*)d_ws;   // 64*328*2 = 41,984 B

    wprep<<<(O_DIM * KPAD + 255) / 256, 256, 0, stream>>>(W, Wf);
    sig_mfma<<<64 * J_DIM * 2, 256, 0, stream>>>(x, Wf, b, out);
}